// Round 13
// baseline (133.846 us; speedup 1.0000x reference)
//
#include <hip/hip_runtime.h>
#include <math.h>

#define B 8
#define NSMI 100
#define NATOM 45
#define ND 145      // NSMI + NATOM
#define NP 1000
#define D 64
#define NROW 1145   // ND + NP rows per batch

#define PROJ_RPB 16
#define PROJ_BPB 72          // ceil(1145/16)
#define ROW_BPB 37           // ceil(145/4)
#define COL_BPB 250          // 1000/4
#define PAIR_ROW_BLKS (B * ROW_BPB)            // 296
#define PAIR_BLKS (PAIR_ROW_BLKS + B * COL_BPB) // 2296

__device__ __forceinline__ float4 f4z() { float4 z; z.x = z.y = z.z = z.w = 0.f; return z; }
__device__ __forceinline__ void f4acc(float4& a, const float4& v) {
    a.x += v.x; a.y += v.y; a.z += v.z; a.w += v.w;
}
__device__ __forceinline__ void acc_relu(float4& acc, const float4& a, const float4& p) {
    acc.x += fmaxf(0.f, a.x + p.x);
    acc.y += fmaxf(0.f, a.y + p.y);
    acc.z += fmaxf(0.f, a.z + p.z);
    acc.w += fmaxf(0.f, a.w + p.w);
}
__device__ __forceinline__ void wave_red_g(float4& v) {
    v.x += __shfl_xor(v.x, 16, 64); v.x += __shfl_xor(v.x, 32, 64);
    v.y += __shfl_xor(v.y, 16, 64); v.y += __shfl_xor(v.y, 32, 64);
    v.z += __shfl_xor(v.z, 16, 64); v.z += __shfl_xor(v.z, 32, 64);
    v.w += __shfl_xor(v.w, 16, 64); v.w += __shfl_xor(v.w, 32, 64);
}

// ============ K1: projection (smi, pro) + drug_gat copy; zero x_sums & out ============
__global__ __launch_bounds__(256) void k_proj2(
    const float* __restrict__ smi_tf, const float* __restrict__ pro_tf,
    const float* __restrict__ drug_gat, const float* __restrict__ w_att,
    const float* __restrict__ b_att,
    float* __restrict__ smi_attss, float* __restrict__ pro_att,
    float* __restrict__ x_sums, float* __restrict__ out)
{
    int blk = blockIdx.x, t = threadIdx.x;
    if (blk == 0) {
        ((float4*)x_sums)[t] = f4z();   // 256 f4 = 1024 floats
        if (t < 16) out[t] = 0.f;
    }
    int b = blk / PROJ_BPB;
    int r0 = (blk - b * PROJ_BPB) * PROJ_RPB;

    __shared__ float4 wl[64 * 17];
    __shared__ float4 rl4[16 * 17];

    #pragma unroll
    for (int i2 = 0; i2 < 4; ++i2) {
        int f = t + 256 * i2;
        float4 v = ((const float4*)w_att)[f];
        wl[(f >> 4) * 17 + (f & 15)] = v;
    }
    int rl = t >> 4, p = t & 15;
    int r = r0 + rl;
    {
        float4 v = f4z();
        if (r < NROW) {
            const float* src;
            if (r < NSMI)      src = smi_tf   + (size_t)(b * NSMI + r) * D;
            else if (r < ND)   src = drug_gat + (size_t)(b * NATOM + (r - NSMI)) * D;
            else               src = pro_tf   + (size_t)(b * NP + (r - ND)) * D;
            v = ((const float4*)src)[p];
        }
        rl4[rl * 17 + p] = v;
    }
    __syncthreads();
    if (r >= NROW) return;
    float4 out4;
    if (r >= NSMI && r < ND) {
        out4 = rl4[rl * 17 + p];
    } else {
        float4 acc = ((const float4*)b_att)[p];
        const float* rowf = (const float*)rl4;
        #pragma unroll
        for (int k = 0; k < 64; ++k) {
            float val = rowf[rl * 68 + k];
            float4 w = wl[k * 17 + p];
            acc.x = fmaf(val, w.x, acc.x);
            acc.y = fmaf(val, w.y, acc.y);
            acc.z = fmaf(val, w.z, acc.z);
            acc.w = fmaf(val, w.w, acc.w);
        }
        out4 = acc;
    }
    if (r < ND) ((float4*)smi_attss)[(size_t)(b * ND + r) * 16 + p] = out4;
    else        ((float4*)pro_att)[(size_t)(b * NP + (r - ND)) * 16 + p] = out4;
}

// ============ K2: pair-sums + gates + atomic mean-pool (no tfs materialization) ============
__global__ __launch_bounds__(512) void k_pair(
    const float4* __restrict__ smi4, const float4* __restrict__ pro4,
    const float* __restrict__ smi_attss, const float* __restrict__ pro_tf,
    const float* __restrict__ w_att, const float* __restrict__ b_att,
    float* __restrict__ x_sums)
{
    __shared__ float4 red[8][4][16];
    __shared__ float vl[4][64];
    __shared__ float gv[4][64];
    int blk = blockIdx.x, t = threadIdx.x;
    int w = t >> 6, lane = t & 63, l = lane & 15, g = lane >> 4;
    int u = w * 4 + g;
    float4 acc0 = f4z(), acc1 = f4z(), acc2 = f4z(), acc3 = f4z();
    int b, base;
    bool isRow = (blk < PAIR_ROW_BLKS);

    if (isRow) {
        b = blk / ROW_BPB;
        base = (blk - b * ROW_BPB) * 4;
        float4 a0 = (base + 0 < ND) ? smi4[(size_t)(b * ND + base + 0) * 16 + l] : f4z();
        float4 a1 = (base + 1 < ND) ? smi4[(size_t)(b * ND + base + 1) * 16 + l] : f4z();
        float4 a2 = (base + 2 < ND) ? smi4[(size_t)(b * ND + base + 2) * 16 + l] : f4z();
        float4 a3 = (base + 3 < ND) ? smi4[(size_t)(b * ND + base + 3) * 16 + l] : f4z();
        const float4* pp = pro4 + (size_t)b * NP * 16 + u * 16 + l;
        #pragma unroll 4
        for (int it = 0; it < 31; ++it) {
            float4 pv = pp[it * 512];
            acc_relu(acc0, a0, pv); acc_relu(acc1, a1, pv);
            acc_relu(acc2, a2, pv); acc_relu(acc3, a3, pv);
        }
        if (u < 8) {
            float4 pv = pp[31 * 512];
            acc_relu(acc0, a0, pv); acc_relu(acc1, a1, pv);
            acc_relu(acc2, a2, pv); acc_relu(acc3, a3, pv);
        }
    } else {
        int cb = blk - PAIR_ROW_BLKS;
        b = cb / COL_BPB;
        base = (cb - b * COL_BPB) * 4;
        float4 p0 = pro4[(size_t)(b * NP + base + 0) * 16 + l];
        float4 p1 = pro4[(size_t)(b * NP + base + 1) * 16 + l];
        float4 p2 = pro4[(size_t)(b * NP + base + 2) * 16 + l];
        float4 p3 = pro4[(size_t)(b * NP + base + 3) * 16 + l];
        const float4* ap = smi4 + (size_t)b * ND * 16 + u * 16 + l;
        #pragma unroll
        for (int it = 0; it < 4; ++it) {
            float4 av = ap[it * 512];
            acc_relu(acc0, av, p0); acc_relu(acc1, av, p1);
            acc_relu(acc2, av, p2); acc_relu(acc3, av, p3);
        }
        if (u < 17) {
            float4 av = ap[4 * 512];
            acc_relu(acc0, av, p0); acc_relu(acc1, av, p1);
            acc_relu(acc2, av, p2); acc_relu(acc3, av, p3);
        }
    }

    wave_red_g(acc0); wave_red_g(acc1); wave_red_g(acc2); wave_red_g(acc3);
    if (lane < 16) {
        red[w][0][l] = acc0; red[w][1][l] = acc1;
        red[w][2][l] = acc2; red[w][3][l] = acc3;
    }
    __syncthreads();
    float invn = isRow ? (1.0f / NP) : (1.0f / ND);
    if (t < 64) {
        int ii = t >> 4, l2 = t & 15;
        float4 s = f4z();
        #pragma unroll
        for (int w2 = 0; w2 < 8; ++w2) f4acc(s, red[w2][ii][l2]);
        vl[ii][l2 * 4 + 0] = s.x * invn;
        vl[ii][l2 * 4 + 1] = s.y * invn;
        vl[ii][l2 * 4 + 2] = s.z * invn;
        vl[ii][l2 * 4 + 3] = s.w * invn;
    }
    __syncthreads();
    if (t < 256) {
        int ii = t >> 6, d = t & 63;
        int r = base + ii;
        bool ok = isRow ? (r < ND) : true;
        float v = 0.f;
        if (ok) {
            float m = b_att[d];
            #pragma unroll
            for (int k = 0; k < 64; ++k) m = fmaf(vl[ii][k], w_att[k * 64 + d], m);
            float gs = 1.f / (1.f + expf(-m));
            size_t idx = isRow ? ((size_t)(b * ND + r) * 64 + d)
                               : ((size_t)(b * NP + r) * 64 + d);
            v = (isRow ? smi_attss[idx] : pro_tf[idx]) * (0.5f + gs);
        }
        gv[ii][d] = v;
    }
    __syncthreads();
    if (t < 64) {
        float s = gv[0][t] + gv[1][t] + gv[2][t] + gv[3][t];
        atomicAdd(&x_sums[b * 128 + (isRow ? 0 : 64) + t], s);
    }
}

// ============ K3: l1+l2 fused. 64 blocks x 512. h1 computed redundantly per block ============
__global__ __launch_bounds__(512) void k_l12(
    const float* __restrict__ x_sums, const float4* __restrict__ w1_4,
    const float* __restrict__ b1, const float4* __restrict__ w2_4,
    const float* __restrict__ b2, float4* __restrict__ h2_4)
{
    __shared__ float4 buf[4096];           // 64 KB, region-reused
    float* xs  = (float*)buf;              // floats [0..1023]
    float* h1f = (float*)buf + 1024;       // floats [1024..9215] = h1[8][1024]
    float4* h1f4 = buf + 256;
    int oc = blockIdx.x, t = threadIdx.x;
    xs[t]       = x_sums[t]       * (((t & 127) < 64) ? (1.0f / ND) : (1.0f / NP));
    xs[t + 512] = x_sums[t + 512] * (((t & 127) < 64) ? (1.0f / ND) : (1.0f / NP));
    __syncthreads();
    // phase 1: full h1 (each thread: one o4-slot x 4 batches, full K=128)
    {
        int o4 = t & 255, bh = t >> 8;
        const float* x0 = xs + (bh * 4 + 0) * 128;
        const float* x1 = xs + (bh * 4 + 1) * 128;
        const float* x2 = xs + (bh * 4 + 2) * 128;
        const float* x3 = xs + (bh * 4 + 3) * 128;
        float4 a0 = f4z(), a1 = f4z(), a2 = f4z(), a3 = f4z();
        #pragma unroll 8
        for (int k = 0; k < 128; ++k) {
            float4 wv = w1_4[(size_t)k * 256 + o4];
            a0.x = fmaf(x0[k], wv.x, a0.x); a0.y = fmaf(x0[k], wv.y, a0.y);
            a0.z = fmaf(x0[k], wv.z, a0.z); a0.w = fmaf(x0[k], wv.w, a0.w);
            a1.x = fmaf(x1[k], wv.x, a1.x); a1.y = fmaf(x1[k], wv.y, a1.y);
            a1.z = fmaf(x1[k], wv.z, a1.z); a1.w = fmaf(x1[k], wv.w, a1.w);
            a2.x = fmaf(x2[k], wv.x, a2.x); a2.y = fmaf(x2[k], wv.y, a2.y);
            a2.z = fmaf(x2[k], wv.z, a2.z); a2.w = fmaf(x2[k], wv.w, a2.w);
            a3.x = fmaf(x3[k], wv.x, a3.x); a3.y = fmaf(x3[k], wv.y, a3.y);
            a3.z = fmaf(x3[k], wv.z, a3.z); a3.w = fmaf(x3[k], wv.w, a3.w);
        }
        float4 bb = ((const float4*)b1)[o4];
        a0.x = fmaxf(a0.x + bb.x, 0.f); a0.y = fmaxf(a0.y + bb.y, 0.f);
        a0.z = fmaxf(a0.z + bb.z, 0.f); a0.w = fmaxf(a0.w + bb.w, 0.f);
        a1.x = fmaxf(a1.x + bb.x, 0.f); a1.y = fmaxf(a1.y + bb.y, 0.f);
        a1.z = fmaxf(a1.z + bb.z, 0.f); a1.w = fmaxf(a1.w + bb.w, 0.f);
        a2.x = fmaxf(a2.x + bb.x, 0.f); a2.y = fmaxf(a2.y + bb.y, 0.f);
        a2.z = fmaxf(a2.z + bb.z, 0.f); a2.w = fmaxf(a2.w + bb.w, 0.f);
        a3.x = fmaxf(a3.x + bb.x, 0.f); a3.y = fmaxf(a3.y + bb.y, 0.f);
        a3.z = fmaxf(a3.z + bb.z, 0.f); a3.w = fmaxf(a3.w + bb.w, 0.f);
        h1f4[(size_t)(bh * 4 + 0) * 256 + o4] = a0;
        h1f4[(size_t)(bh * 4 + 1) * 256 + o4] = a1;
        h1f4[(size_t)(bh * 4 + 2) * 256 + o4] = a2;
        h1f4[(size_t)(bh * 4 + 3) * 256 + o4] = a3;
    }
    __syncthreads();
    // phase 2: l2 slice (4 output-f4 per block)
    int ol = t & 3, g = t >> 2;
    int o4g = oc * 4 + ol;
    float4 acc[8];
    #pragma unroll
    for (int b = 0; b < 8; ++b) acc[b] = f4z();
    #pragma unroll
    for (int kk = 0; kk < 8; ++kk) {
        int k = g * 8 + kk;
        float4 wv = w2_4[(size_t)k * 256 + o4g];
        #pragma unroll
        for (int b = 0; b < 8; ++b) {
            float hv = h1f[b * 1024 + k];
            acc[b].x = fmaf(hv, wv.x, acc[b].x);
            acc[b].y = fmaf(hv, wv.y, acc[b].y);
            acc[b].z = fmaf(hv, wv.z, acc[b].z);
            acc[b].w = fmaf(hv, wv.w, acc[b].w);
        }
    }
    __syncthreads();                 // h1 reads done; buf free for reduction
    #pragma unroll
    for (int b = 0; b < 8; ++b) buf[g * 32 + ol * 8 + b] = acc[b];
    __syncthreads();
    int u = t & 31, gg = t >> 5;
    float4 s = f4z();
    #pragma unroll
    for (int j = 0; j < 8; ++j) f4acc(s, buf[(gg * 8 + j) * 32 + u]);
    buf[gg * 256 + u] = s;
    __syncthreads();
    if (t < 32) {
        float4 v = f4z();
        #pragma unroll
        for (int gg2 = 0; gg2 < 16; ++gg2) f4acc(v, buf[gg2 * 256 + t]);
        int olr = t >> 3, b = t & 7;
        float4 bb = ((const float4*)b2)[oc * 4 + olr];
        v.x = fmaxf(v.x + bb.x, 0.f); v.y = fmaxf(v.y + bb.y, 0.f);
        v.z = fmaxf(v.z + bb.z, 0.f); v.w = fmaxf(v.w + bb.w, 0.f);
        h2_4[b * 256 + oc * 4 + olr] = v;
    }
}

// ============ K4: l3+l4 fused. 32 blocks x 512. atomicAdd partial dots into out ============
__global__ __launch_bounds__(512) void k_l34(
    const float4* __restrict__ h2_4, const float4* __restrict__ w3_4,
    const float* __restrict__ b3, const float* __restrict__ w4p,
    const float* __restrict__ b4p, float* __restrict__ out)
{
    __shared__ float4 buf[4096];
    float* lds_h = (float*)buf;
    int oc = blockIdx.x, t = threadIdx.x;
    #pragma unroll
    for (int j = 0; j < 4; ++j) buf[t + 512 * j] = h2_4[t + 512 * j];
    __syncthreads();
    int ol = t & 3, g = t >> 2;
    int o4 = oc * 4 + ol;            // < 128
    float4 acc[8];
    #pragma unroll
    for (int b = 0; b < 8; ++b) acc[b] = f4z();
    #pragma unroll
    for (int kk = 0; kk < 8; ++kk) {
        int k = g * 8 + kk;
        float4 wv = w3_4[(size_t)k * 128 + o4];
        #pragma unroll
        for (int b = 0; b < 8; ++b) {
            float hv = lds_h[b * 1024 + k];
            acc[b].x = fmaf(hv, wv.x, acc[b].x);
            acc[b].y = fmaf(hv, wv.y, acc[b].y);
            acc[b].z = fmaf(hv, wv.z, acc[b].z);
            acc[b].w = fmaf(hv, wv.w, acc[b].w);
        }
    }
    __syncthreads();
    #pragma unroll
    for (int b = 0; b < 8; ++b) buf[g * 32 + ol * 8 + b] = acc[b];
    __syncthreads();
    int u = t & 31, gg = t >> 5;
    float4 s = f4z();
    #pragma unroll
    for (int j = 0; j < 8; ++j) f4acc(s, buf[(gg * 8 + j) * 32 + u]);
    buf[gg * 256 + u] = s;
    __syncthreads();
    if (t < 32) {
        float4 v = f4z();
        #pragma unroll
        for (int gg2 = 0; gg2 < 16; ++gg2) f4acc(v, buf[gg2 * 256 + t]);
        int olr = t >> 3, b = t & 7;
        float4 bb = ((const float4*)b3)[oc * 4 + olr];
        v.x = fmaxf(v.x + bb.x, 0.f); v.y = fmaxf(v.y + bb.y, 0.f);
        v.z = fmaxf(v.z + bb.z, 0.f); v.w = fmaxf(v.w + bb.w, 0.f);
        // l4 partial: 4 h3 values (o' = oc*16 + olr*4 + 0..3) x w4[o'][0..1]
        int ob = oc * 16 + olr * 4;
        float p0 = v.x * w4p[(ob + 0) * 2] + v.y * w4p[(ob + 1) * 2]
                 + v.z * w4p[(ob + 2) * 2] + v.w * w4p[(ob + 3) * 2];
        float p1 = v.x * w4p[(ob + 0) * 2 + 1] + v.y * w4p[(ob + 1) * 2 + 1]
                 + v.z * w4p[(ob + 2) * 2 + 1] + v.w * w4p[(ob + 3) * 2 + 1];
        p0 += __shfl_xor(p0, 8, 64);  p0 += __shfl_xor(p0, 16, 64);
        p1 += __shfl_xor(p1, 8, 64);  p1 += __shfl_xor(p1, 16, 64);
        if (olr == 0) {               // t<8: b = t
            if (oc == 0) { p0 += b4p[0]; p1 += b4p[1]; }
            atomicAdd(&out[b * 2 + 0], p0);
            atomicAdd(&out[b * 2 + 1], p1);
        }
    }
}

extern "C" void kernel_launch(void* const* d_in, const int* in_sizes, int n_in,
                              void* d_out, int out_size, void* d_ws, size_t ws_size,
                              hipStream_t stream)
{
    const float* smi_tf   = (const float*)d_in[0];
    const float* pro_tf   = (const float*)d_in[1];
    const float* drug_gat = (const float*)d_in[2];
    const float* w_att    = (const float*)d_in[3];
    const float* b_att    = (const float*)d_in[4];
    const float* w1 = (const float*)d_in[5];
    const float* b1 = (const float*)d_in[6];
    const float* w2 = (const float*)d_in[7];
    const float* b2 = (const float*)d_in[8];
    const float* w3 = (const float*)d_in[9];
    const float* b3 = (const float*)d_in[10];
    const float* w4 = (const float*)d_in[11];
    const float* b4 = (const float*)d_in[12];
    float* out = (float*)d_out;

    float* ws = (float*)d_ws;
    float* smi_attss = ws;                    // 74240
    float* pro_att   = smi_attss + 74240;     // 512000
    float* x_sums    = pro_att + 512000;      // 1024
    float* h2        = x_sums + 1024;         // 8192

    k_proj2<<<B * PROJ_BPB, 256, 0, stream>>>(smi_tf, pro_tf, drug_gat, w_att, b_att,
                                              smi_attss, pro_att, x_sums, out);
    k_pair <<<PAIR_BLKS, 512, 0, stream>>>((const float4*)smi_attss, (const float4*)pro_att,
                                           smi_attss, pro_tf, w_att, b_att, x_sums);
    k_l12  <<<64, 512, 0, stream>>>(x_sums, (const float4*)w1, b1,
                                    (const float4*)w2, b2, (float4*)h2);
    k_l34  <<<32, 512, 0, stream>>>((const float4*)h2, (const float4*)w3, b3,
                                    w4, b4, out);
}